// Round 6
// baseline (472.433 us; speedup 1.0000x reference)
//
#include <hip/hip_runtime.h>
#include <cstdint>
#include <cstddef>

constexpr int Bn = 64, Tn = 1024, Hn = 256, Kn = 4;
constexpr int MROWS = 32;           // output t-rows per block
constexpr int SROWS = MROWS + 2;    // staged input rows
constexpr int SST   = 36;           // LDS srow stride
constexpr int CHI   = 4;            // i-values per B chunk
constexpr int HHALF = 128;          // channels staged per A-half
constexpr int NCHT  = Hn / CHI;     // 64 chunks total

// Pack conv_w [o][i][dt] -> wP[(dt*256+i)][o]
__global__ __launch_bounds__(256) void pack_w_k(const float* __restrict__ conv_w,
                                                float* __restrict__ wP) {
  int o  = threadIdx.x;
  int kk = blockIdx.x;              // kk = dt*256 + i
  int dt = kk >> 8, i = kk & 255;
  wP[kk * Hn + o] = conv_w[o * (Hn * 3) + i * 3 + dt];
}

// Fused conv1d(k=3,pad=1)+bias+ReLU+Linear(256->4): em[B,T,4] fp32.
// Thread tile 8 t-rows x 4 n-cols. A staged in channel-HALVES (18,432 B),
// B double-buffered CHI=4 chunks (24,576 B) -> LDS 43,008 B -> 3 blocks/CU.
// Barriers: 66 per block (vs 128 at CHI=2).
__global__ __launch_bounds__(256, 2) void emis_k(const float* __restrict__ x,
    const float* __restrict__ wP, const float* __restrict__ conv_b,
    const float* __restrict__ lin_w, const float* __restrict__ lin_b,
    float* __restrict__ em) {
  __shared__ float xsT[HHALF * SST];         // [chanLocal][srow], 18,432 B
  __shared__ float bufB[2][3 * CHI][Hn];     // 24,576 B

  const int b  = blockIdx.y, t0 = blockIdx.x * MROWS;
  const int tid = threadIdx.x;
  const int ng4 = tid & 63;         // cols ng4*4 .. +3
  const int mg  = tid >> 6;         // rows 8*mg .. +7

  const float4* x4 = reinterpret_cast<const float4*>(x + (size_t)b * Tn * Hn);
  const float4* w4 = reinterpret_cast<const float4*>(wP);

  // ---- stage one A channel-half: chans [k0, k0+128), transposed ----
  auto stageA = [&](int k0) {
    for (int idx = tid; idx < SROWS * (HHALF / 4); idx += 256) {  // 1088
      int row = idx >> 5, c4 = idx & 31;
      int t = t0 - 1 + row;
      float4 v = make_float4(0.f, 0.f, 0.f, 0.f);
      if (t >= 0 && t < Tn) v = x4[t * (Hn / 4) + (k0 >> 2) + c4];
      int i = c4 << 2;
      xsT[(i + 0) * SST + row] = v.x;
      xsT[(i + 1) * SST + row] = v.y;
      xsT[(i + 2) * SST + row] = v.z;
      xsT[(i + 3) * SST + row] = v.w;
    }
  };

  // ---- prologue: A half 0, B chunk 0 (abs chans 0..3) ----
  stageA(0);
  #pragma unroll
  for (int j = 0; j < 3; ++j) {
    int fq = tid + j * 256;          // 0..767
    int r = fq >> 6;                 // 0..11 = dt*4+ii
    float4 v = w4[((r >> 2) * 256 + 0 + (r & 3)) * 64 + (fq & 63)];
    *reinterpret_cast<float4*>(&bufB[0][r][(fq & 63) * 4]) = v;
  }
  __syncthreads();

  float acc[8][4];
  #pragma unroll
  for (int rr = 0; rr < 8; ++rr)
    #pragma unroll
    for (int j = 0; j < 4; ++j) acc[rr][j] = 0.f;

  float4 p[3];
  #pragma unroll 1
  for (int cc = 0; cc < NCHT; ++cc) {
    const int cur = cc & 1;
    const bool more = (cc + 1 < NCHT);
    if (more) {                      // issue-early: next chunk's global loads
      const int iB = (cc + 1) * CHI; // absolute channel base
      #pragma unroll
      for (int j = 0; j < 3; ++j) {
        int fq = tid + j * 256;
        int r = fq >> 6;
        p[j] = w4[((r >> 2) * 256 + iB + (r & 3)) * 64 + (fq & 63)];
      }
    }
    if (cc == 32) {                  // switch to A half 1 (chans 128..255)
      stageA(HHALF);
      __syncthreads();
    }
    const int iLoc0 = (cc & 31) * CHI;   // chan base within current half
    #pragma unroll
    for (int ii = 0; ii < CHI; ++ii) {
      const float* ap = &xsT[(iLoc0 + ii) * SST + 8 * mg];  // wave-broadcast
      const float4 a01 = *reinterpret_cast<const float4*>(ap);
      const float4 a23 = *reinterpret_cast<const float4*>(ap + 4);
      const float2 a45 = *reinterpret_cast<const float2*>(ap + 8);
      const float a[10] = {a01.x, a01.y, a01.z, a01.w,
                           a23.x, a23.y, a23.z, a23.w, a45.x, a45.y};
      #pragma unroll
      for (int dt = 0; dt < 3; ++dt) {
        const float4 bq = *reinterpret_cast<const float4*>(
            &bufB[cur][dt * CHI + ii][ng4 * 4]);   // 64 lanes x 16B contiguous
        const float bb[4] = {bq.x, bq.y, bq.z, bq.w};
        #pragma unroll
        for (int rr = 0; rr < 8; ++rr)
          #pragma unroll
          for (int j = 0; j < 4; ++j)
            acc[rr][j] = fmaf(a[rr + dt], bb[j], acc[rr][j]);
      }
    }
    if (more) {                      // write-late into the other buffer
      #pragma unroll
      for (int j = 0; j < 3; ++j) {
        int fq = tid + j * 256;
        *reinterpret_cast<float4*>(&bufB[cur ^ 1][fq >> 6][(fq & 63) * 4]) = p[j];
      }
    }
    __syncthreads();
  }

  // ---- Epilogue: +conv_b, ReLU, x lin_w^T over this thread's 4 cols ----
  float pem[8][4];
  #pragma unroll
  for (int rr = 0; rr < 8; ++rr)
    #pragma unroll
    for (int k = 0; k < 4; ++k) pem[rr][k] = 0.f;

  const int n0 = ng4 * 4;
  #pragma unroll
  for (int j = 0; j < 4; ++j) {
    const int n = n0 + j;
    const float cb = conv_b[n];
    const float l0 = lin_w[0 * Hn + n];
    const float l1 = lin_w[1 * Hn + n];
    const float l2 = lin_w[2 * Hn + n];
    const float l3 = lin_w[3 * Hn + n];
    #pragma unroll
    for (int rr = 0; rr < 8; ++rr) {
      float v = fmaxf(acc[rr][j] + cb, 0.f);
      pem[rr][0] = fmaf(v, l0, pem[rr][0]);
      pem[rr][1] = fmaf(v, l1, pem[rr][1]);
      pem[rr][2] = fmaf(v, l2, pem[rr][2]);
      pem[rr][3] = fmaf(v, l3, pem[rr][3]);
    }
  }
  #pragma unroll
  for (int rr = 0; rr < 8; ++rr)
    #pragma unroll
    for (int k = 0; k < 4; ++k) {
      float v = pem[rr][k];
      v += __shfl_xor(v, 1);
      v += __shfl_xor(v, 2);
      v += __shfl_xor(v, 4);
      v += __shfl_xor(v, 8);
      v += __shfl_xor(v, 16);
      v += __shfl_xor(v, 32);
      pem[rr][k] = v;
    }
  if (ng4 == 0) {
    #pragma unroll
    for (int rr = 0; rr < 8; ++rr) {
      const int m = 8 * mg + rr;
      float4 o;
      o.x = pem[rr][0] + lin_b[0];
      o.y = pem[rr][1] + lin_b[1];
      o.z = pem[rr][2] + lin_b[2];
      o.w = pem[rr][3] + lin_b[3];
      *reinterpret_cast<float4*>(em + (size_t)(b * Tn + t0 + m) * 4) = o;
    }
  }
}

// byte-map composition c(k) = a(b(k))
__device__ __forceinline__ unsigned int compose_map(unsigned int a, unsigned int b) {
#if __has_builtin(__builtin_amdgcn_perm)
  return __builtin_amdgcn_perm(a, a, b);
#else
  unsigned int c = 0;
  #pragma unroll
  for (int k = 0; k < 4; ++k) {
    unsigned int sel = (b >> (8 * k)) & 0xffu;
    c |= ((a >> (8 * sel)) & 0xffu) << (8 * k);
  }
  return c;
#endif
}

// quad_perm broadcast of lane J (within each 4-lane quad) via DPP
template <int J>
__device__ __forceinline__ float qb(float v) {
  return __int_as_float(__builtin_amdgcn_update_dpp(
      0, __float_as_int(v), (J * 0x55), 0xf, 0xf, true));
}

// One quad-parallel Viterbi step for lane k: c_j = bcast_j(s) + tr[j][k];
// s = max(c0..c3) + e. Values bitwise-identical to the scalar VSTEP
// (same adds, same max set; fp max is exact).
#define PSTEP(EV, T)                                                       \
  {                                                                        \
    shf[((T) - 1) * 4 + kk] = s;                                           \
    float c0 = qb<0>(s) + trc0;                                            \
    float c1 = qb<1>(s) + trc1;                                            \
    float c2 = qb<2>(s) + trc2;                                            \
    float c3 = qb<3>(s) + trc3;                                            \
    s = fmaxf(fmaxf(c0, c1), fmaxf(c2, c3)) + (EV);                        \
  }

// CRF Viterbi decode. Forward: 4-lane quad-parallel scan (lane k owns
// state k), 8-deep per-lane emission prefetch. Backtrace: 64 lanes rebuild
// argmax maps (exact per-candidate (s+tr)+e form, first-wins), v_perm
// suffix-scan (integer-exact).
__global__ __launch_bounds__(64) void viterbi_k(const float* __restrict__ em,
    const float* __restrict__ cstart, const float* __restrict__ cend,
    const float* __restrict__ ctrans, int* __restrict__ out) {
  __shared__ float4 se[Tn];          // emissions, 16 KB
  __shared__ float4 sh[Tn - 1];      // score vector BEFORE step t+1, 16 KB
  __shared__ int s_last;
  const int b = blockIdx.x, lane = threadIdx.x;
  const float4* e4 = reinterpret_cast<const float4*>(em + (size_t)b * Tn * Kn);
  for (int i = lane; i < Tn; i += 64) se[i] = e4[i];
  float tr[4][4];
  #pragma unroll
  for (int j = 0; j < 4; ++j)
    #pragma unroll
    for (int k = 0; k < 4; ++k) tr[j][k] = ctrans[j * 4 + k];
  __syncthreads();

  if (lane < 4) {
    const int kk = lane;
    const float* sef = reinterpret_cast<const float*>(se);
    float* shf = reinterpret_cast<float*>(sh);
    const float trc0 = ctrans[0 * 4 + kk];
    const float trc1 = ctrans[1 * 4 + kk];
    const float trc2 = ctrans[2 * 4 + kk];
    const float trc3 = ctrans[3 * 4 + kk];
    float s = cstart[kk] + sef[kk];
    float e[8];
    #pragma unroll
    for (int d = 0; d < 8; ++d) e[d] = sef[(1 + d) * 4 + kk];
    int t = 1;
    #pragma unroll 1
    for (int g = 0; g < 127; ++g, t += 8) {   // t = 1..1016
      float f[8];
      #pragma unroll
      for (int d = 0; d < 8; ++d) f[d] = e[d];
      #pragma unroll
      for (int d = 0; d < 8; ++d) e[d] = sef[(t + 8 + d) * 4 + kk];  // may
      // read a few words past se[] into sh[] on the last group: harmless.
      PSTEP(f[0], t);     PSTEP(f[1], t + 1);
      PSTEP(f[2], t + 2); PSTEP(f[3], t + 3);
      PSTEP(f[4], t + 4); PSTEP(f[5], t + 5);
      PSTEP(f[6], t + 6); PSTEP(f[7], t + 7);
    }
    // tail: t = 1017..1023 (e[0..6] hold se[1017..1023])
    PSTEP(e[0], 1017); PSTEP(e[1], 1018); PSTEP(e[2], 1019);
    PSTEP(e[3], 1020); PSTEP(e[4], 1021); PSTEP(e[5], 1022);
    PSTEP(e[6], 1023);
    s += cend[kk];
    float f0 = __shfl(s, 0), f1 = __shfl(s, 1);
    float f2 = __shfl(s, 2), f3 = __shfl(s, 3);
    if (kk == 0) {
      int tag = 0; float bf = f0;
      if (f1 > bf) { bf = f1; tag = 1; }
      if (f2 > bf) { bf = f2; tag = 2; }
      if (f3 > bf) { bf = f3; tag = 3; }
      s_last = tag;
    }
  }
  __syncthreads();

  // ---- parallel backtrace: lane owns maps t in [16*lane, 16*lane+15] ----
  const unsigned int ID = 0x03020100u;
  unsigned int mloc[16];
  const int t0 = lane * 16;
  #pragma unroll
  for (int k = 0; k < 16; ++k) {
    const int t = t0 + k;
    if (t < Tn - 1) {
      const float4 s = sh[t];
      const float4 e = se[t + 1];
      const float sj[4] = {s.x, s.y, s.z, s.w};
      const float ev[4] = {e.x, e.y, e.z, e.w};
      unsigned int mw = 0;
      #pragma unroll
      for (int kk = 0; kk < 4; ++kk) {
        float best = (sj[0] + tr[0][kk]) + ev[kk];
        int bi = 0;
        #pragma unroll
        for (int j = 1; j < 4; ++j) {
          float cc = (sj[j] + tr[j][kk]) + ev[kk];
          if (cc > best) { best = cc; bi = j; }
        }
        mw |= (unsigned)bi << (8 * kk);
      }
      mloc[k] = mw;
    } else {
      mloc[k] = ID;
    }
  }
  unsigned int P = mloc[15];
  #pragma unroll
  for (int k = 14; k >= 0; --k) P = compose_map(mloc[k], P);
  #pragma unroll
  for (int d = 1; d < 64; d <<= 1) {
    unsigned int q = (unsigned int)__shfl_down((int)P, d);
    if (lane + d > 63) q = ID;
    P = compose_map(P, q);
  }
  unsigned int E = (unsigned int)__shfl_down((int)P, 1);  // exclusive suffix
  if (lane == 63) E = ID;
  const int last = s_last;
  unsigned int tag = (E >> (8 * last)) & 3u;
  int* ob = out + (size_t)b * Tn;
  #pragma unroll
  for (int k = 15; k >= 0; --k) {
    tag = (mloc[k] >> (8 * tag)) & 3u;
    ob[t0 + k] = (int)tag;
  }
}

extern "C" void kernel_launch(void* const* d_in, const int* in_sizes, int n_in,
                              void* d_out, int out_size, void* d_ws, size_t ws_size,
                              hipStream_t stream) {
  const float* x      = (const float*)d_in[0];
  const float* conv_w = (const float*)d_in[1];
  const float* conv_b = (const float*)d_in[2];
  const float* lin_w  = (const float*)d_in[3];
  const float* lin_b  = (const float*)d_in[4];
  const float* cstart = (const float*)d_in[5];
  const float* cend   = (const float*)d_in[6];
  const float* ctrans = (const float*)d_in[7];
  int* out = (int*)d_out;

  float* wP = (float*)d_ws;                      // 768*256 floats
  float* em = wP + 768 * 256;                    // 64*1024*4 floats

  pack_w_k<<<768, 256, 0, stream>>>(conv_w, wP);
  emis_k<<<dim3(Tn / MROWS, Bn), 256, 0, stream>>>(x, wP, conv_b, lin_w, lin_b, em);
  viterbi_k<<<Bn, 64, 0, stream>>>(em, cstart, cend, ctrans, out);
}

// Round 7
// 347.684 us; speedup vs baseline: 1.3588x; 1.3588x over previous
//
#include <hip/hip_runtime.h>
#include <cstdint>
#include <cstddef>

constexpr int Bn = 64, Tn = 1024, Hn = 256, Kn = 4;
constexpr int MROWS = 32;           // output t-rows per block
constexpr int SROWS = MROWS + 2;    // staged input rows
constexpr int SST   = 36;           // LDS srow stride (16B-aligned)
constexpr int CHI   = 2;            // i-values per B chunk
constexpr int NCH   = Hn / CHI;     // 128 chunks

// Pack conv_w [o][i][dt] -> wP[(dt*256+i)][o]
__global__ __launch_bounds__(256) void pack_w_k(const float* __restrict__ conv_w,
                                                float* __restrict__ wP) {
  int o  = threadIdx.x;
  int kk = blockIdx.x;              // kk = dt*256 + i
  int dt = kk >> 8, i = kk & 255;
  wP[kk * Hn + o] = conv_w[o * (Hn * 3) + i * 3 + dt];
}

// async global->LDS, 16B per lane (dest = wave-uniform base + lane*16)
__device__ __forceinline__ void gload_lds16(const float* g, float* l) {
  __builtin_amdgcn_global_load_lds(
      (const __attribute__((address_space(1))) void*)g,
      (__attribute__((address_space(3))) void*)l, 16, 0, 0);
}

// Fused conv1d(k=3,pad=1)+bias+ReLU+Linear(256->4): em[B,T,4] fp32.
// Round-5 structure (thread tile 8 t-rows x 4 n-cols, CHI=2 double-buffered
// B, LDS 49,152 B -> 3 blocks/CU) with B staging via global_load_lds width=16
// (no VGPR round-trip, no ds_write, staging drains on vmcnt only).
__global__ __launch_bounds__(256, 2) void emis_k(const float* __restrict__ x,
    const float* __restrict__ wP, const float* __restrict__ conv_b,
    const float* __restrict__ lin_w, const float* __restrict__ lin_b,
    float* __restrict__ em) {
  __shared__ float xsT[Hn * SST];            // [chan][srow], 36,864 B
  __shared__ float bufB[2][3 * CHI][Hn];     // 12,288 B (total 49,152)

  const int b  = blockIdx.y, t0 = blockIdx.x * MROWS;
  const int tid = threadIdx.x;
  const int ng4 = tid & 63;         // cols ng4*4 .. +3
  const int mg  = tid >> 6;         // rows 8*mg .. +7 (one mg per wave)
  const int lane = tid & 63;

  // ---- B staging: 6 rows (r = dt*2+ii) per chunk; row r<4 by wave r,
  // rows 4,5 by waves 0,1. Per row: 64 lanes x 16 B = 1024 B. ----
  auto stageB = [&](int dst, int c) {
    int r0 = mg;                                   // rows 0..3
    {
      const int dt = r0 >> 1, ii = r0 & 1;
      const float* g = wP + (size_t)((dt << 8) + c * CHI + ii) * Hn + lane * 4;
      gload_lds16(g, &bufB[dst][r0][lane * 4]);
    }
    if (mg < 2) {                                  // rows 4,5
      const int r1 = 4 + mg;
      const int dt = r1 >> 1, ii = r1 & 1;
      const float* g = wP + (size_t)((dt << 8) + c * CHI + ii) * Hn + lane * 4;
      gload_lds16(g, &bufB[dst][r1][lane * 4]);
    }
  };

  // ---- Stage A transposed: [chan][srow], srow = t-(t0-1) in 0..33 ----
  const float4* x4 = reinterpret_cast<const float4*>(x + (size_t)b * Tn * Hn);
  stageB(0, 0);
  for (int idx = tid; idx < SROWS * (Hn / 4); idx += 256) {
    int row = idx >> 6, c4 = idx & 63;
    int t = t0 - 1 + row;
    float4 v = make_float4(0.f, 0.f, 0.f, 0.f);
    if (t >= 0 && t < Tn) v = x4[t * (Hn / 4) + c4];
    int i = c4 << 2;
    xsT[(i + 0) * SST + row] = v.x;
    xsT[(i + 1) * SST + row] = v.y;
    xsT[(i + 2) * SST + row] = v.z;
    xsT[(i + 3) * SST + row] = v.w;
  }
  __syncthreads();

  float acc[8][4];
  #pragma unroll
  for (int rr = 0; rr < 8; ++rr)
    #pragma unroll
    for (int j = 0; j < 4; ++j) acc[rr][j] = 0.f;

  #pragma unroll 1
  for (int c = 0; c < NCH; ++c) {
    const int cur = c & 1;
    if (c + 1 < NCH) stageB(cur ^ 1, c + 1);  // async, lands during compute
    #pragma unroll
    for (int ii = 0; ii < CHI; ++ii) {
      const int i = c * CHI + ii;
      const float* ap = &xsT[i * SST + 8 * mg];     // wave-broadcast reads
      const float4 a01 = *reinterpret_cast<const float4*>(ap);
      const float4 a23 = *reinterpret_cast<const float4*>(ap + 4);
      const float2 a45 = *reinterpret_cast<const float2*>(ap + 8);
      const float a[10] = {a01.x, a01.y, a01.z, a01.w,
                           a23.x, a23.y, a23.z, a23.w, a45.x, a45.y};
      #pragma unroll
      for (int dt = 0; dt < 3; ++dt) {
        const float4 bq = *reinterpret_cast<const float4*>(
            &bufB[cur][dt * CHI + ii][ng4 * 4]);   // 64 lanes x 16B contiguous
        const float bb[4] = {bq.x, bq.y, bq.z, bq.w};
        #pragma unroll
        for (int rr = 0; rr < 8; ++rr)
          #pragma unroll
          for (int j = 0; j < 4; ++j)
            acc[rr][j] = fmaf(a[rr + dt], bb[j], acc[rr][j]);
      }
    }
    __syncthreads();   // drains vmcnt (gll landed) + orders buffer reuse
  }

  // ---- Epilogue: +conv_b, ReLU, x lin_w^T over this thread's 4 cols ----
  float pem[8][4];
  #pragma unroll
  for (int rr = 0; rr < 8; ++rr)
    #pragma unroll
    for (int k = 0; k < 4; ++k) pem[rr][k] = 0.f;

  const int n0 = ng4 * 4;
  #pragma unroll
  for (int j = 0; j < 4; ++j) {
    const int n = n0 + j;
    const float cb = conv_b[n];
    const float l0 = lin_w[0 * Hn + n];
    const float l1 = lin_w[1 * Hn + n];
    const float l2 = lin_w[2 * Hn + n];
    const float l3 = lin_w[3 * Hn + n];
    #pragma unroll
    for (int rr = 0; rr < 8; ++rr) {
      float v = fmaxf(acc[rr][j] + cb, 0.f);
      pem[rr][0] = fmaf(v, l0, pem[rr][0]);
      pem[rr][1] = fmaf(v, l1, pem[rr][1]);
      pem[rr][2] = fmaf(v, l2, pem[rr][2]);
      pem[rr][3] = fmaf(v, l3, pem[rr][3]);
    }
  }
  #pragma unroll
  for (int rr = 0; rr < 8; ++rr)
    #pragma unroll
    for (int k = 0; k < 4; ++k) {
      float v = pem[rr][k];
      v += __shfl_xor(v, 1);
      v += __shfl_xor(v, 2);
      v += __shfl_xor(v, 4);
      v += __shfl_xor(v, 8);
      v += __shfl_xor(v, 16);
      v += __shfl_xor(v, 32);
      pem[rr][k] = v;
    }
  if (ng4 == 0) {
    #pragma unroll
    for (int rr = 0; rr < 8; ++rr) {
      const int m = 8 * mg + rr;
      float4 o;
      o.x = pem[rr][0] + lin_b[0];
      o.y = pem[rr][1] + lin_b[1];
      o.z = pem[rr][2] + lin_b[2];
      o.w = pem[rr][3] + lin_b[3];
      *reinterpret_cast<float4*>(em + (size_t)(b * Tn + t0 + m) * 4) = o;
    }
  }
}

// byte-map composition c(k) = a(b(k))
__device__ __forceinline__ unsigned int compose_map(unsigned int a, unsigned int b) {
#if __has_builtin(__builtin_amdgcn_perm)
  return __builtin_amdgcn_perm(a, a, b);
#else
  unsigned int c = 0;
  #pragma unroll
  for (int k = 0; k < 4; ++k) {
    unsigned int sel = (b >> (8 * k)) & 0xffu;
    c |= ((a >> (8 * sel)) & 0xffu) << (8 * k);
  }
  return c;
#endif
}

// quad_perm broadcast of lane J (within each 4-lane quad) via DPP
template <int J>
__device__ __forceinline__ float qb(float v) {
  return __int_as_float(__builtin_amdgcn_update_dpp(
      0, __float_as_int(v), (J * 0x55), 0xf, 0xf, true));
}

// One quad-parallel Viterbi step for lane k: c_j = bcast_j(s) + tr[j][k];
// s = max(c0..c3) + e. Values bitwise-identical to the scalar form
// (same adds, same max set; fp max is exact).
#define PSTEP(EV, T)                                                       \
  {                                                                        \
    shf[((T) - 1) * 4 + kk] = s;                                           \
    float c0 = qb<0>(s) + trc0;                                            \
    float c1 = qb<1>(s) + trc1;                                            \
    float c2 = qb<2>(s) + trc2;                                            \
    float c3 = qb<3>(s) + trc3;                                            \
    s = fmaxf(fmaxf(c0, c1), fmaxf(c2, c3)) + (EV);                        \
  }

// CRF Viterbi decode. Forward: 4-lane quad-parallel scan (lane k owns
// state k), 8-deep per-lane emission prefetch. Backtrace: 64 lanes rebuild
// argmax maps (exact per-candidate (s+tr)+e form, first-wins), v_perm
// suffix-scan (integer-exact).
__global__ __launch_bounds__(64) void viterbi_k(const float* __restrict__ em,
    const float* __restrict__ cstart, const float* __restrict__ cend,
    const float* __restrict__ ctrans, int* __restrict__ out) {
  __shared__ float4 se[Tn];          // emissions, 16 KB
  __shared__ float4 sh[Tn - 1];      // score vector BEFORE step t+1, 16 KB
  __shared__ int s_last;
  const int b = blockIdx.x, lane = threadIdx.x;
  const float4* e4 = reinterpret_cast<const float4*>(em + (size_t)b * Tn * Kn);
  for (int i = lane; i < Tn; i += 64) se[i] = e4[i];
  float tr[4][4];
  #pragma unroll
  for (int j = 0; j < 4; ++j)
    #pragma unroll
    for (int k = 0; k < 4; ++k) tr[j][k] = ctrans[j * 4 + k];
  __syncthreads();

  if (lane < 4) {
    const int kk = lane;
    const float* sef = reinterpret_cast<const float*>(se);
    float* shf = reinterpret_cast<float*>(sh);
    const float trc0 = ctrans[0 * 4 + kk];
    const float trc1 = ctrans[1 * 4 + kk];
    const float trc2 = ctrans[2 * 4 + kk];
    const float trc3 = ctrans[3 * 4 + kk];
    float s = cstart[kk] + sef[kk];
    float e[8];
    #pragma unroll
    for (int d = 0; d < 8; ++d) e[d] = sef[(1 + d) * 4 + kk];
    int t = 1;
    #pragma unroll 1
    for (int g = 0; g < 127; ++g, t += 8) {   // t = 1..1016
      float f[8];
      #pragma unroll
      for (int d = 0; d < 8; ++d) f[d] = e[d];
      #pragma unroll
      for (int d = 0; d < 8; ++d) e[d] = sef[(t + 8 + d) * 4 + kk];  // last
      // group reads a few words into sh[] (defined LDS): harmless.
      PSTEP(f[0], t);     PSTEP(f[1], t + 1);
      PSTEP(f[2], t + 2); PSTEP(f[3], t + 3);
      PSTEP(f[4], t + 4); PSTEP(f[5], t + 5);
      PSTEP(f[6], t + 6); PSTEP(f[7], t + 7);
    }
    // tail: t = 1017..1023 (e[0..6] hold se[1017..1023])
    PSTEP(e[0], 1017); PSTEP(e[1], 1018); PSTEP(e[2], 1019);
    PSTEP(e[3], 1020); PSTEP(e[4], 1021); PSTEP(e[5], 1022);
    PSTEP(e[6], 1023);
    s += cend[kk];
    float f0 = __shfl(s, 0), f1 = __shfl(s, 1);
    float f2 = __shfl(s, 2), f3 = __shfl(s, 3);
    if (kk == 0) {
      int tag = 0; float bf = f0;
      if (f1 > bf) { bf = f1; tag = 1; }
      if (f2 > bf) { bf = f2; tag = 2; }
      if (f3 > bf) { bf = f3; tag = 3; }
      s_last = tag;
    }
  }
  __syncthreads();

  // ---- parallel backtrace: lane owns maps t in [16*lane, 16*lane+15] ----
  const unsigned int ID = 0x03020100u;
  unsigned int mloc[16];
  const int t0 = lane * 16;
  #pragma unroll
  for (int k = 0; k < 16; ++k) {
    const int t = t0 + k;
    if (t < Tn - 1) {
      const float4 s = sh[t];
      const float4 e = se[t + 1];
      const float sj[4] = {s.x, s.y, s.z, s.w};
      const float ev[4] = {e.x, e.y, e.z, e.w};
      unsigned int mw = 0;
      #pragma unroll
      for (int kk = 0; kk < 4; ++kk) {
        float best = (sj[0] + tr[0][kk]) + ev[kk];
        int bi = 0;
        #pragma unroll
        for (int j = 1; j < 4; ++j) {
          float cc = (sj[j] + tr[j][kk]) + ev[kk];
          if (cc > best) { best = cc; bi = j; }
        }
        mw |= (unsigned)bi << (8 * kk);
      }
      mloc[k] = mw;
    } else {
      mloc[k] = ID;
    }
  }
  unsigned int P = mloc[15];
  #pragma unroll
  for (int k = 14; k >= 0; --k) P = compose_map(mloc[k], P);
  #pragma unroll
  for (int d = 1; d < 64; d <<= 1) {
    unsigned int q = (unsigned int)__shfl_down((int)P, d);
    if (lane + d > 63) q = ID;
    P = compose_map(P, q);
  }
  unsigned int E = (unsigned int)__shfl_down((int)P, 1);  // exclusive suffix
  if (lane == 63) E = ID;
  const int last = s_last;
  unsigned int tag = (E >> (8 * last)) & 3u;
  int* ob = out + (size_t)b * Tn;
  #pragma unroll
  for (int k = 15; k >= 0; --k) {
    tag = (mloc[k] >> (8 * tag)) & 3u;
    ob[t0 + k] = (int)tag;
  }
}

extern "C" void kernel_launch(void* const* d_in, const int* in_sizes, int n_in,
                              void* d_out, int out_size, void* d_ws, size_t ws_size,
                              hipStream_t stream) {
  const float* x      = (const float*)d_in[0];
  const float* conv_w = (const float*)d_in[1];
  const float* conv_b = (const float*)d_in[2];
  const float* lin_w  = (const float*)d_in[3];
  const float* lin_b  = (const float*)d_in[4];
  const float* cstart = (const float*)d_in[5];
  const float* cend   = (const float*)d_in[6];
  const float* ctrans = (const float*)d_in[7];
  int* out = (int*)d_out;

  float* wP = (float*)d_ws;                      // 768*256 floats
  float* em = wP + 768 * 256;                    // 64*1024*4 floats

  pack_w_k<<<768, 256, 0, stream>>>(conv_w, wP);
  emis_k<<<dim3(Tn / MROWS, Bn), 256, 0, stream>>>(x, wP, conv_b, lin_w, lin_b, em);
  viterbi_k<<<Bn, 64, 0, stream>>>(em, cstart, cend, ctrans, out);
}